// Round 10
// baseline (84.646 us; speedup 1.0000x reference)
//
#include <hip/hip_runtime.h>
#include <hip/hip_fp16.h>

typedef __attribute__((ext_vector_type(8)))  _Float16 half8;
typedef __attribute__((ext_vector_type(16))) float    f32x16;

#define B_   16
#define NPTS 4096                      // points per batch (N == M == 4096)
#define TPTS (B_ * NPTS)               // 65536 points per tensor

constexpr int BLK  = 512;              // 8 waves per block
constexpr int WV   = 8;
constexpr int QF   = 2;                // query fragments per wave (64 queries)
constexpr int QPW  = 32 * QF;          // 64 queries per wave
constexpr int TSPL = 2;                // target splits (waves sharing a query group)
constexpr int QG   = WV / TSPL;        // 4 query groups per block
constexpr int QPB  = QG * QPW;         // 256 queries per block
constexpr int NQC  = NPTS / QPB;       // 16 query chunks
constexpr int TPS  = NPTS / TSPL;      // 2048 targets per split
constexpr int TPW  = TPS / 32;         // 64 tiles of 32 targets per wave
constexpr int NIT  = TPW / 2;          // 32 loop steps (2 tiles each)
constexpr int NBLK = 2 * B_ * NQC;     // 512 blocks (2 per CU)

__device__ __forceinline__ float min3f(float a, float b, float c) {
    return fminf(fminf(a, b), c);      // -> v_min3_f32
}

__device__ __forceinline__ float tree16(const f32x16& d) {
    float a0 = min3f(d[0],  d[1],  d[2]);
    float a1 = min3f(d[3],  d[4],  d[5]);
    float a2 = min3f(d[6],  d[7],  d[8]);
    float a3 = min3f(d[9],  d[10], d[11]);
    float a4 = min3f(d[12], d[13], d[14]);
    return fminf(min3f(a0, a1, a2), min3f(a3, a4, d[15]));
}

// ------------------------------------------------------------------
// R10: hoist ALL fp16 conversion out of the hot kernel. Evidence: R8/R9
// show the sweep (~13us) is MFMA+VALU issue-bound at a LOW core clock
// (~0.6-0.9 GHz inferred from MfmaUtil/VALUBusy vs instruction counts);
// the ~18us non-sweep is dominated by per-block point conversion that is
// 32x REDUNDANT across blocks (each of 512 blocks re-converts the same
// 4096 targets). A tiny prep kernel precomputes A-frag rows (uint4) and
// B-frag packs (uint2+q2) for both tensors into d_ws; the main kernel's
// staging collapses to 8x global_load_lds (direct L2->LDS DMA, no VALU,
// no ds_write). Sweep = exactly R4's proven form (permlane/prefetch/
// setprio all removed: null or VALU-negative).
// Math identical: A-row [-2x,-2y,-2z,g2hi,g2lo,0,0,0], B-frag
// [x,y,z,1,1,0,0,0] -> D = 2(|g|^2 - 2 q.g); d^2 = 0.5*minD + |q|^2.

__global__ __launch_bounds__(512) void chamfer_prep(
        const float* __restrict__ pred, const float* __restrict__ gt,
        uint4* __restrict__ AF, uint2* __restrict__ BP, float* __restrict__ Q2) {
    const int t = blockIdx.x >> 7;                    // tensor 0=pred, 1=gt
    const int i = (blockIdx.x & 127) * 512 + threadIdx.x;   // point 0..65535
    const float* p = (t ? gt : pred) + i * 3;
    __half hx = __float2half(p[0]);
    __half hy = __float2half(p[1]);
    __half hz = __float2half(p[2]);
    float fx = __half2float(hx), fy = __half2float(hy), fz = __half2float(hz);
    float g2 = fmaf(fx, fx, fmaf(fy, fy, fz * fz));
    // A-form (as target): [-2x,-2y,-2z,g2hi,g2lo,0,0,0]
    __half ax = __float2half(-2.0f * fx);
    __half ay = __float2half(-2.0f * fy);
    __half az = __float2half(-2.0f * fz);
    __half g2hi = __float2half(g2);
    __half g2lo = __float2half(g2 - __half2float(g2hi));
    uint4 w;
    w.x = (unsigned)__half_as_ushort(ax) | ((unsigned)__half_as_ushort(ay) << 16);
    w.y = (unsigned)__half_as_ushort(az) | ((unsigned)__half_as_ushort(g2hi) << 16);
    w.z = (unsigned)__half_as_ushort(g2lo);
    w.w = 0u;
    AF[t * TPTS + i] = w;
    // B-form (as query): {x,y}, {z,1.0}; |q|^2 in f32
    uint2 bp;
    bp.x = (unsigned)__half_as_ushort(hx) | ((unsigned)__half_as_ushort(hy) << 16);
    bp.y = (unsigned)__half_as_ushort(hz) | (0x3C00u << 16);
    BP[t * TPTS + i] = bp;
    Q2[t * TPTS + i] = g2;
}

__global__ __launch_bounds__(BLK, 4) void chamfer_mfma(
        const uint4* __restrict__ AF, const uint2* __restrict__ BP,
        const float* __restrict__ Q2,
        float* __restrict__ accum, unsigned* __restrict__ counter,
        float* __restrict__ out) {
    const int qc  = blockIdx.x;
    const int b   = blockIdx.y;
    const int dir = blockIdx.z;
    const int qt  = dir;                     // queries: dir0=pred(0), dir1=gt(1)
    const int tt  = dir ^ 1;                 // targets: the other tensor

    __shared__ uint4 sh[NPTS];               // 64 KB: all targets as A-frag rows
    __shared__ float sred[WV][QPW];          // 2 KB: per-wave per-query min d^2
    __shared__ float ps[QG];

    const int tid  = threadIdx.x;
    const int lane = tid & 63;
    const int wv   = tid >> 6;
    const int m    = lane & 31;
    const int qg   = wv >> 1;                // query group 0..3
    const int ts   = wv & 1;                 // target split 0..1

    // ---- B fragments: precomputed packs (2 loads + consts each) ----
    const int qbase_i = qt * TPTS + b * NPTS + qc * QPB + qg * QPW;
    half8 bfrag[QF];
    float q2[QF];
#pragma unroll
    for (int f = 0; f < QF; ++f) {
        const int idx = qbase_i + f * 32 + m;
        const uint2 bp = BP[idx];
        q2[f] = Q2[idx];
        uint4 bu;
        bu.x = bp.x;
        bu.y = bp.y;
        bu.z = 0x3C00u;                      // {1.0, 0}
        bu.w = 0u;
        bfrag[f] = __builtin_bit_cast(half8, bu);
    }

    f32x16 zero;
#pragma unroll
    for (int i = 0; i < 16; ++i) zero[i] = 0.0f;

    // ---- stage ALL 4096 target rows: direct global->LDS DMA ----
    const uint4* afp = AF + tt * TPTS + b * NPTS;
#pragma unroll
    for (int k = 0; k < NPTS / BLK; ++k) {   // 8 x 16B per thread
        const int j = k * BLK + tid;
        __builtin_amdgcn_global_load_lds(
            (const __attribute__((address_space(1))) void*)(afp + j),
            (__attribute__((address_space(3))) void*)(&sh[j]), 16, 0, 0);
    }
    __syncthreads();

    // ---- sweep this wave's 64 tiles, 2 tiles x 2 qfrags per step
    //      (R4's proven inner loop, verbatim) ----
    const uint4* shp = sh + ts * TPS + m;    // lanes L, L+32 share addr (free 2-way)
    float mn0 = 1e30f, mn1 = 1e30f;
#pragma unroll 8
    for (int t = 0; t < NIT; ++t) {
        uint4 au0 = shp[t * 64];             // tile 2t   (byte off t*1024)
        uint4 au1 = shp[t * 64 + 32];        // tile 2t+1 (byte off t*1024+512)
        half8 a0 = __builtin_bit_cast(half8, au0);
        half8 a1 = __builtin_bit_cast(half8, au1);
        f32x16 d00 = __builtin_amdgcn_mfma_f32_32x32x16_f16(a0, bfrag[0], zero, 0, 0, 0);
        f32x16 d01 = __builtin_amdgcn_mfma_f32_32x32x16_f16(a0, bfrag[1], zero, 0, 0, 0);
        f32x16 d10 = __builtin_amdgcn_mfma_f32_32x32x16_f16(a1, bfrag[0], zero, 0, 0, 0);
        f32x16 d11 = __builtin_amdgcn_mfma_f32_32x32x16_f16(a1, bfrag[1], zero, 0, 0, 0);
        float t00 = tree16(d00);
        float t01 = tree16(d01);
        float t10 = tree16(d10);
        float t11 = tree16(d11);
        mn0 = min3f(mn0, t00, t10);
        mn1 = min3f(mn1, t01, t11);
    }

    // rows split across lane halves: full 32-row min needs lane ^ 32
    float v0 = fminf(mn0, __shfl_xor(mn0, 32));
    float v1 = fminf(mn1, __shfl_xor(mn1, 32));
    float dd0 = fmaxf(fmaf(0.5f, v0, q2[0]), 0.0f);  // undo K-dup, fold |q|^2
    float dd1 = fmaxf(fmaf(0.5f, v1, q2[1]), 0.0f);
    if (lane < 32) {                                 // lanes 32-63 hold duplicates
        sred[wv][m]      = dd0;
        sred[wv][m + 32] = dd1;
    }
    __syncthreads();

    // ---- combine 2 target splits per query, sqrt, block-sum ----
    float s = 0.0f;
    if (wv < QG) {                               // threads 0..255 = 256 queries
        const int g  = wv;                       // query group 0..3
        const int mm = lane;                     // query within group 0..63
        float d = fminf(sred[g * 2 + 0][mm], sred[g * 2 + 1][mm]);
        s = sqrtf(d);
        // butterfly sum over this wave's 64 lanes
#pragma unroll
        for (int off = 32; off; off >>= 1) s += __shfl_xor(s, off);
        if (lane == 0) ps[g] = s;
    }
    __syncthreads();

    if (tid == 0) {
        float bs = ps[0] + ps[1] + ps[2] + ps[3];
        atomicAdd(accum, bs);
        __threadfence();
        if (atomicAdd(counter, 1u) == NBLK - 1) {   // last block finalizes
            float total = atomicAdd(accum, 0.0f);   // coherent read
            float loss  = total * (1.0f / (float)(B_ * NPTS));
            out[0] = loss;          // WEIGHT * loss, WEIGHT = 1
            out[1] = loss;          // helper_loss
            out[2] = 0.1f * loss;   // helper_cderr = p1 chamfer * xyz_unit
        }
    }
}

// ------------------------------------------------------------------
extern "C" void kernel_launch(void* const* d_in, const int* in_sizes, int n_in,
                              void* d_out, int out_size, void* d_ws, size_t ws_size,
                              hipStream_t stream) {
    const float* pred = (const float*)d_in[0];
    const float* gt   = (const float*)d_in[1];
    float*    out     = (float*)d_out;
    float*    accum   = (float*)d_ws;
    unsigned* counter = (unsigned*)d_ws + 1;
    char*     base    = (char*)d_ws;
    uint4*    AF      = (uint4*)(base + 1024);                    // 2 MB
    uint2*    BP      = (uint2*)(base + 1024 + (2u << 20));       // 1 MB
    float*    Q2      = (float*)(base + 1024 + (3u << 20));       // 512 KB

    hipMemsetAsync(d_ws, 0, 8, stream);
    chamfer_prep<<<dim3(256), dim3(512), 0, stream>>>(pred, gt, AF, BP, Q2);
    chamfer_mfma<<<dim3(NQC, B_, 2), BLK, 0, stream>>>(AF, BP, Q2, accum, counter, out);
}

// Round 13
// 80.448 us; speedup vs baseline: 1.0522x; 1.0522x over previous
//
#include <hip/hip_runtime.h>
#include <hip/hip_fp16.h>

typedef __attribute__((ext_vector_type(8)))  _Float16 half8;
typedef __attribute__((ext_vector_type(16))) float    f32x16;

#define B_   16
#define NPTS 4096                      // points per batch (N == M == 4096)

constexpr int BLK  = 512;              // 8 waves per block
constexpr int WV   = 8;
constexpr int QF   = 2;                // query fragments per wave (64 queries)
constexpr int QPW  = 32 * QF;          // 64 queries per wave
constexpr int TSPL = 2;                // target splits (waves sharing a query group)
constexpr int QG   = WV / TSPL;        // 4 query groups per block
constexpr int QPB  = QG * QPW;         // 256 queries per block
constexpr int NQC  = NPTS / QPB;       // 16 query chunks
constexpr int TPS  = NPTS / TSPL;      // 2048 targets per split
constexpr int TPW  = TPS / 32;         // 64 tiles of 32 targets per wave
constexpr int NIT  = TPW / 2;          // 32 loop steps (2 tiles each)
constexpr int NBLK = 2 * B_ * NQC;     // 512 blocks (2 per CU)

__device__ __forceinline__ float min3f(float a, float b, float c) {
    return fminf(fminf(a, b), c);      // -> v_min3_f32
}

__device__ __forceinline__ float tree16(const f32x16& d) {
    float a0 = min3f(d[0],  d[1],  d[2]);
    float a1 = min3f(d[3],  d[4],  d[5]);
    float a2 = min3f(d[6],  d[7],  d[8]);
    float a3 = min3f(d[9],  d[10], d[11]);
    float a4 = min3f(d[12], d[13], d[14]);
    return fminf(min3f(a0, a1, a2), min3f(a3, a4, d[15]));
}

// ------------------------------------------------------------------
// R13 = restore best passing kernel (R7, 78.8us). Cooperative launch
// (R11/R12) no-ops in this harness (unchecked launch error under graph
// capture; out never written -> deterministic absmax 0.3125). Final
// ledger: bench ~79 = harness ws-repoison fill ~40.5 + graph/dispatch
// fixed ~8 + kernel ~31 (sweep ~13 at VALU min-fold issue floor for the
// observed DVFS clock; non-sweep ~18 = launch ramp/tail, survived six
// structural attacks). Sweep min-cost is within ~10% of the 2-dist/inst
// v_min3 bound; direction-shared S-tiles are arithmetically worse
// (col-min = 1.0 lane-op/dist vs 0.53). This is the practical floor.
// Math: A-row [-2x,-2y,-2z,g2hi,g2lo,0,0,0], B-frag [x,y,z,1,1,0,0,0]
// -> D = 2(|g|^2 - 2 q.g); d^2 = 0.5*minD + |q|^2.
__global__ __launch_bounds__(BLK, 4) void chamfer_mfma(
        const float* __restrict__ pred, const float* __restrict__ gt,
        float* __restrict__ accum, unsigned* __restrict__ counter,
        float* __restrict__ out) {
    const int qc  = blockIdx.x;
    const int b   = blockIdx.y;
    const int dir = blockIdx.z;
    const float* qsrc = dir ? gt   : pred;   // queries
    const float* tsrc = dir ? pred : gt;     // targets

    __shared__ uint4 sh[NPTS];               // 64 KB: all targets as A-frag rows
    __shared__ float sred[WV][QPW];          // 2 KB: per-wave per-query min d^2
    __shared__ float ps[QG];

    const int tid  = threadIdx.x;
    const int lane = tid & 63;
    const int wv   = tid >> 6;
    const int m    = lane & 31;
    const int qg   = wv >> 1;                // query group 0..3
    const int ts   = wv & 1;                 // target split 0..1

    // ---- B fragments: this lane's two queries (cols m and m+32) ----
    const float* qbase = qsrc + (b * NPTS + qc * QPB + qg * QPW) * 3;
    half8 bfrag[QF];
    float q2[QF];
#pragma unroll
    for (int f = 0; f < QF; ++f) {
        const float* qp = qbase + (f * 32 + m) * 3;
        __half hqx = __float2half(qp[0]);
        __half hqy = __float2half(qp[1]);
        __half hqz = __float2half(qp[2]);
        float fqx = __half2float(hqx), fqy = __half2float(hqy), fqz = __half2float(hqz);
        q2[f] = fmaf(fqx, fqx, fmaf(fqy, fqy, fqz * fqz));
        uint4 bu;
        bu.x = (unsigned)__half_as_ushort(hqx) | ((unsigned)__half_as_ushort(hqy) << 16);
        bu.y = (unsigned)__half_as_ushort(hqz) | (0x3C00u << 16);   // {z, 1.0}
        bu.z = 0x3C00u;                                             // {1.0, 0}
        bu.w = 0u;
        bfrag[f] = __builtin_bit_cast(half8, bu);
    }

    f32x16 zero;
#pragma unroll
    for (int i = 0; i < 16; ++i) zero[i] = 0.0f;

    // ---- stage ALL 4096 targets as A-frag rows (float4-vectorized) ----
    const float4* tp4 = reinterpret_cast<const float4*>(tsrc + b * NPTS * 3);
#pragma unroll
    for (int k = 0; k < NPTS / (4 * BLK); ++k) {    // 2 super-iters x 4 points
        const int tq = k * BLK + tid;               // quad index
        const float4 f0 = tp4[tq * 3 + 0];
        const float4 f1 = tp4[tq * 3 + 1];
        const float4 f2 = tp4[tq * 3 + 2];
        const float px[4] = {f0.x, f0.w, f1.z, f2.y};
        const float py[4] = {f0.y, f1.x, f1.w, f2.z};
        const float pz[4] = {f0.z, f1.y, f2.x, f2.w};
#pragma unroll
        for (int i = 0; i < 4; ++i) {
            __half hx = __float2half(px[i]);
            __half hy = __float2half(py[i]);
            __half hz = __float2half(pz[i]);
            float fx = __half2float(hx), fy = __half2float(hy), fz = __half2float(hz);
            float g2 = fmaf(fx, fx, fmaf(fy, fy, fz * fz));
            __half ax = __float2half(-2.0f * fx);
            __half ay = __float2half(-2.0f * fy);
            __half az = __float2half(-2.0f * fz);
            __half g2hi = __float2half(g2);
            __half g2lo = __float2half(g2 - __half2float(g2hi));
            uint4 w;
            w.x = (unsigned)__half_as_ushort(ax) | ((unsigned)__half_as_ushort(ay) << 16);
            w.y = (unsigned)__half_as_ushort(az) | ((unsigned)__half_as_ushort(g2hi) << 16);
            w.z = (unsigned)__half_as_ushort(g2lo);
            w.w = 0u;
            sh[tq * 4 + i] = w;
        }
    }
    __syncthreads();

    // ---- sweep this wave's 64 tiles, 2 tiles x 2 qfrags per step,
    //      depth-1 prefetch (load t+1 while computing t) ----
    const uint4* shp = sh + ts * TPS + m;    // lane base (lanes L, L+32 share addr)
    float mn0 = 1e30f, mn1 = 1e30f;
    uint4 au0 = shp[0];                      // tile 0
    uint4 au1 = shp[32];                     // tile 1
#pragma unroll 8
    for (int t = 0; t < NIT; ++t) {
        const int tn = (t + 1) & (NIT - 1);  // wraps to 0 on last iter (harmless)
        uint4 nx0 = shp[tn * 64];
        uint4 nx1 = shp[tn * 64 + 32];
        half8 a0 = __builtin_bit_cast(half8, au0);
        half8 a1 = __builtin_bit_cast(half8, au1);
        __builtin_amdgcn_s_setprio(1);
        f32x16 d00 = __builtin_amdgcn_mfma_f32_32x32x16_f16(a0, bfrag[0], zero, 0, 0, 0);
        f32x16 d01 = __builtin_amdgcn_mfma_f32_32x32x16_f16(a0, bfrag[1], zero, 0, 0, 0);
        f32x16 d10 = __builtin_amdgcn_mfma_f32_32x32x16_f16(a1, bfrag[0], zero, 0, 0, 0);
        f32x16 d11 = __builtin_amdgcn_mfma_f32_32x32x16_f16(a1, bfrag[1], zero, 0, 0, 0);
        __builtin_amdgcn_s_setprio(0);
        float t00 = tree16(d00);
        float t01 = tree16(d01);
        float t10 = tree16(d10);
        float t11 = tree16(d11);
        mn0 = min3f(mn0, t00, t10);
        mn1 = min3f(mn1, t01, t11);
        au0 = nx0;
        au1 = nx1;
    }

    // rows split across lane halves: full 32-row min needs lane ^ 32
    float v0 = fminf(mn0, __shfl_xor(mn0, 32));
    float v1 = fminf(mn1, __shfl_xor(mn1, 32));
    float dd0 = fmaxf(fmaf(0.5f, v0, q2[0]), 0.0f);  // undo K-dup, fold |q|^2
    float dd1 = fmaxf(fmaf(0.5f, v1, q2[1]), 0.0f);
    if (lane < 32) {                                 // lanes 32-63 hold duplicates
        sred[wv][m]      = dd0;
        sred[wv][m + 32] = dd1;
    }
    __syncthreads();

    // ---- combine 2 target splits per query, sqrt, block-sum ----
    float s = 0.0f;
    if (wv < QG) {                               // threads 0..255 = 256 queries
        const int g  = wv;                       // query group 0..3
        const int mm = lane;                     // query within group 0..63
        float d = fminf(sred[g * 2 + 0][mm], sred[g * 2 + 1][mm]);
        s = sqrtf(d);
        // butterfly sum over this wave's 64 lanes
#pragma unroll
        for (int off = 32; off; off >>= 1) s += __shfl_xor(s, off);
        if (lane == 0) ps[g] = s;
    }
    __syncthreads();

    if (tid == 0) {
        float bs = ps[0] + ps[1] + ps[2] + ps[3];
        atomicAdd(accum, bs);
        __threadfence();
        if (atomicAdd(counter, 1u) == NBLK - 1) {   // last block finalizes
            float total = atomicAdd(accum, 0.0f);   // coherent read
            float loss  = total * (1.0f / (float)(B_ * NPTS));
            out[0] = loss;          // WEIGHT * loss, WEIGHT = 1
            out[1] = loss;          // helper_loss
            out[2] = 0.1f * loss;   // helper_cderr = p1 chamfer * xyz_unit
        }
    }
}

// ------------------------------------------------------------------
extern "C" void kernel_launch(void* const* d_in, const int* in_sizes, int n_in,
                              void* d_out, int out_size, void* d_ws, size_t ws_size,
                              hipStream_t stream) {
    const float* pred = (const float*)d_in[0];
    const float* gt   = (const float*)d_in[1];
    float*    out     = (float*)d_out;
    float*    accum   = (float*)d_ws;
    unsigned* counter = (unsigned*)d_ws + 1;

    hipMemsetAsync(d_ws, 0, 8, stream);
    chamfer_mfma<<<dim3(NQC, B_, 2), BLK, 0, stream>>>(pred, gt, accum, counter, out);
}